// Round 4
// baseline (149.232 us; speedup 1.0000x reference)
//
#include <hip/hip_runtime.h>

// 2 rows/thread, register-resident. Round-4 change: ALL exp/rcp-heavy paths
// moved off the transcendental unit where profitable.
//  - Calibrated from R2/R3 counters: v_exp_f32 / v_rcp_f32 cost ~16 cy per
//    wave64 inst (4-lane trans unit); trans was ~70% of busy cycles.
//  - pexp2(): packed deg-4 range-reduced 2^x on v2f = ~24 plain-VALU cy per
//    PAIR (~12 cy/exp vs 16 trans). Args are <= 0 (max-shifted) except
//    sigmoid, which is clamped to <= 30.
//  - Sigmoid reciprocals batch-inverted (Montgomery, groups of 4): 64 rcp ->
//    16 rcp + 9 muls/group. Safe: d = 1+2^la, la<=30 => prod4 <= 2^121.
// Weights staged in LDS once per block (broadcast ds_read). Packed fp32
// (v_pk_fma_f32) everywhere.

typedef float v2f __attribute__((ext_vector_type(2)));

#define LOG2E 1.44269504088896340736f
#define ROWS 2

__device__ __forceinline__ float rcpf(float a) { return __builtin_amdgcn_rcpf(a); }

// packed 2^a; clamps a below at -126 (result ~0). Requires a <= ~127.
__device__ __forceinline__ v2f pexp2(v2f a) {
    a = __builtin_elementwise_max(a, (v2f)(-126.f));
    v2f kf;
    kf[0] = __builtin_rintf(a[0]);            // v_rndne_f32
    kf[1] = __builtin_rintf(a[1]);
    v2f f = a - kf;                           // f in [-0.5, 0.5]
    // 2^f Taylor deg-4: rel err ~4e-5 on [-0.5,0.5]
    v2f p = (v2f)(0.0096181291076285f);
    p = p * f + (v2f)(0.0555041086648216f);
    p = p * f + (v2f)(0.2402265069591007f);
    p = p * f + (v2f)(0.6931471805599453f);
    p = p * f + (v2f)(1.0f);
    v2f r;
    r[0] = ldexpf(p[0], (int)kf[0]);          // v_cvt_i32_f32 + v_ldexp_f32
    r[1] = ldexpf(p[1], (int)kf[1]);
    return r;
}

__global__ __launch_bounds__(256, 4) void fused_attn_mlp(
    const float* __restrict__ x,
    const float* __restrict__ wq,
    const float* __restrict__ wk,
    const float* __restrict__ wv,
    const float* __restrict__ Wh,
    const float* __restrict__ bh,
    const float* __restrict__ Wo,
    const float* __restrict__ bo,
    float* __restrict__ out,
    int B)
{
    // ---- stage weights into LDS (once per block) ----
    __shared__ float sWh[64 * 16];   // row-major as given
    __shared__ float sWoT[64 * 8];   // sWoT[h*8+o] = Wo[o*64+h]
    __shared__ float sbh[64];

    const int t = threadIdx.x;
    {
        const float4* src = reinterpret_cast<const float4*>(Wh);
        float4* dst = reinterpret_cast<float4*>(sWh);
        dst[t] = src[t];
    }
    #pragma unroll
    for (int r = t; r < 512; r += 256) {
        const int h = r >> 3, o = r & 7;
        sWoT[h * 8 + o] = Wo[o * 64 + h];
    }
    if (t < 64) sbh[t] = bh[t];
    __syncthreads();

    const int b0 = blockIdx.x * (256 * ROWS) + t;
    bool valid[ROWS];
    #pragma unroll
    for (int r = 0; r < ROWS; ++r) valid[r] = (b0 + r * 256) < B;

    // ---- load x rows ----
    float xs[ROWS][16];
    v2f xv2[ROWS][8];
    #pragma unroll
    for (int r = 0; r < ROWS; ++r) {
        if (valid[r]) {
            const float4* xr = reinterpret_cast<const float4*>(x) + (size_t)(b0 + r * 256) * 4;
            float4 a0 = xr[0], a1 = xr[1], a2 = xr[2], a3 = xr[3];
            xs[r][0]=a0.x; xs[r][1]=a0.y; xs[r][2]=a0.z; xs[r][3]=a0.w;
            xs[r][4]=a1.x; xs[r][5]=a1.y; xs[r][6]=a1.z; xs[r][7]=a1.w;
            xs[r][8]=a2.x; xs[r][9]=a2.y; xs[r][10]=a2.z; xs[r][11]=a2.w;
            xs[r][12]=a3.x; xs[r][13]=a3.y; xs[r][14]=a3.z; xs[r][15]=a3.w;
        } else {
            #pragma unroll
            for (int i = 0; i < 16; ++i) xs[r][i] = 0.f;
        }
        #pragma unroll
        for (int p = 0; p < 8; ++p) { v2f v; v[0]=xs[r][2*p]; v[1]=xs[r][2*p+1]; xv2[r][p]=v; }
    }

    // ---- attention block 1 (D=16), exp2 domain ----
    const float kq1 = wk[0] * wq[0] * LOG2E;
    const float v1  = wv[0];

    float xmx[ROWS], xmn[ROWS];
    #pragma unroll
    for (int r = 0; r < ROWS; ++r) {
        float mx = xs[r][0], mn = xs[r][0];
        #pragma unroll
        for (int i = 1; i < 16; ++i) { mx = fmaxf(mx, xs[r][i]); mn = fminf(mn, xs[r][i]); }
        xmx[r] = mx; xmn[r] = mn;
    }

    v2f o1v[ROWS][8];
    #pragma unroll
    for (int r = 0; r < ROWS; ++r)
        #pragma unroll
        for (int p = 0; p < 8; ++p) o1v[r][p] = (v2f)(0.f);

    #pragma unroll
    for (int i = 0; i < 16; ++i) {
        v2f e2[ROWS][8];
        float w[ROWS];
        #pragma unroll
        for (int r = 0; r < ROWS; ++r) {
            const float c = kq1 * xs[r][i];
            const float m = fmaxf(c * xmx[r], c * xmn[r]);   // exact attained max -> args <= 0
            v2f cc; cc[0]=c; cc[1]=c;
            v2f mm; mm[0]=m; mm[1]=m;
            v2f sv = (v2f)(0.f);
            #pragma unroll
            for (int p = 0; p < 8; ++p) {
                v2f e = pexp2(cc * xv2[r][p] - mm);
                e2[r][p] = e;
                sv += e;
            }
            w[r] = v1 * xs[r][i] * rcpf(sv[0] + sv[1]);
        }
        #pragma unroll
        for (int r = 0; r < ROWS; ++r) {
            v2f ww; ww[0]=w[r]; ww[1]=w[r];
            #pragma unroll
            for (int p = 0; p < 8; ++p) o1v[r][p] += ww * e2[r][p];
        }
    }

    // ---- fused MLP: 16 -> 64 sigmoid -> 8; sigmoids in groups of 4 with
    //      batch-inverted reciprocals ----
    v2f x2v[ROWS][4];
    #pragma unroll
    for (int r = 0; r < ROWS; ++r)
        #pragma unroll
        for (int p = 0; p < 4; ++p) { v2f v; v[0]=bo[2*p]; v[1]=bo[2*p+1]; x2v[r][p]=v; }

    #pragma unroll 2
    for (int g = 0; g < 16; ++g) {
        float apre[ROWS][4];
        #pragma unroll
        for (int hh = 0; hh < 4; ++hh) {
            const int h = g * 4 + hh;
            const v2f* wh = reinterpret_cast<const v2f*>(sWh + h * 16);
            v2f whr[8];
            #pragma unroll
            for (int p = 0; p < 8; ++p) whr[p] = wh[p];
            #pragma unroll
            for (int r = 0; r < ROWS; ++r) {
                v2f acc = whr[0] * o1v[r][0];
                #pragma unroll
                for (int p = 1; p < 8; ++p) acc += whr[p] * o1v[r][p];
                apre[r][hh] = acc[0] + acc[1] + sbh[h];
            }
        }
        float sg[ROWS][4];
        #pragma unroll
        for (int r = 0; r < ROWS; ++r) {
            v2f la0; la0[0] = apre[r][0]; la0[1] = apre[r][1];
            v2f la1; la1[0] = apre[r][2]; la1[1] = apre[r][3];
            la0 = __builtin_elementwise_min(la0 * (v2f)(-LOG2E), (v2f)(30.f));
            la1 = __builtin_elementwise_min(la1 * (v2f)(-LOG2E), (v2f)(30.f));
            v2f e0 = pexp2(la0), e1 = pexp2(la1);
            const float d0 = 1.f + e0[0], d1 = 1.f + e0[1];
            const float d2 = 1.f + e1[0], d3 = 1.f + e1[1];
            // Montgomery batch inversion: d in [1, 1+2^30], prod4 <= 2^121
            const float p01  = d0 * d1;
            const float p012 = p01 * d2;
            const float rq   = rcpf(p012 * d3);
            const float i3 = rq * p012;
            const float tq = rq * d3;      // 1/(d0 d1 d2)
            const float i2 = tq * p01;
            const float t2 = tq * d2;      // 1/(d0 d1)
            const float i1 = t2 * d0;
            const float i0 = t2 * d1;
            sg[r][0]=i0; sg[r][1]=i1; sg[r][2]=i2; sg[r][3]=i3;
        }
        #pragma unroll
        for (int hh = 0; hh < 4; ++hh) {
            const int h = g * 4 + hh;
            const v2f* wo = reinterpret_cast<const v2f*>(sWoT + h * 8);
            v2f wor[4];
            #pragma unroll
            for (int p = 0; p < 4; ++p) wor[p] = wo[p];
            #pragma unroll
            for (int r = 0; r < ROWS; ++r) {
                v2f sgv; sgv[0]=sg[r][hh]; sgv[1]=sg[r][hh];
                #pragma unroll
                for (int p = 0; p < 4; ++p) x2v[r][p] += wor[p] * sgv;
            }
        }
    }

    // ---- attention block 2 (D=8), exp2 domain; LOG2E folded into o2 ----
    const float kq2 = wk[1] * wq[1] * LOG2E;
    const float v2s = wv[1] * LOG2E;

    float ys[ROWS][8];
    float ymx[ROWS], ymn[ROWS];
    #pragma unroll
    for (int r = 0; r < ROWS; ++r) {
        #pragma unroll
        for (int i = 0; i < 8; ++i) ys[r][i] = x2v[r][i >> 1][i & 1];
        float mx = ys[r][0], mn = ys[r][0];
        #pragma unroll
        for (int i = 1; i < 8; ++i) { mx = fmaxf(mx, ys[r][i]); mn = fminf(mn, ys[r][i]); }
        ymx[r] = mx; ymn[r] = mn;
    }

    v2f o2v[ROWS][4];
    #pragma unroll
    for (int r = 0; r < ROWS; ++r)
        #pragma unroll
        for (int p = 0; p < 4; ++p) o2v[r][p] = (v2f)(0.f);

    #pragma unroll
    for (int i = 0; i < 8; ++i) {
        v2f e2[ROWS][4];
        float w[ROWS];
        #pragma unroll
        for (int r = 0; r < ROWS; ++r) {
            const float c = kq2 * ys[r][i];
            const float m = fmaxf(c * ymx[r], c * ymn[r]);
            v2f cc; cc[0]=c; cc[1]=c;
            v2f mm; mm[0]=m; mm[1]=m;
            v2f sv = (v2f)(0.f);
            #pragma unroll
            for (int p = 0; p < 4; ++p) {
                v2f e = pexp2(cc * x2v[r][p] - mm);
                e2[r][p] = e;
                sv += e;
            }
            w[r] = v2s * ys[r][i] * rcpf(sv[0] + sv[1]);
        }
        #pragma unroll
        for (int r = 0; r < ROWS; ++r) {
            v2f ww; ww[0]=w[r]; ww[1]=w[r];
            #pragma unroll
            for (int p = 0; p < 4; ++p) o2v[r][p] += ww * e2[r][p];
        }
    }

    // ---- final softmax (log2 domain) + dot with x[8:16] ----
    #pragma unroll
    for (int r = 0; r < ROWS; ++r) {
        float o2s[8];
        #pragma unroll
        for (int i = 0; i < 8; ++i) o2s[i] = o2v[r][i >> 1][i & 1];
        float m2 = o2s[0];
        #pragma unroll
        for (int i = 1; i < 8; ++i) m2 = fmaxf(m2, o2s[i]);
        v2f mm2; mm2[0]=m2; mm2[1]=m2;
        v2f se = (v2f)(0.f), de = (v2f)(0.f);
        #pragma unroll
        for (int p = 0; p < 4; ++p) {
            v2f e = pexp2(o2v[r][p] - mm2);
            se += e;
            v2f xp; xp[0]=xs[r][8+2*p]; xp[1]=xs[r][9+2*p];
            de += xp * e;
        }
        if (valid[r]) out[b0 + r * 256] = (de[0] + de[1]) * rcpf(se[0] + se[1]);
    }
}

extern "C" void kernel_launch(void* const* d_in, const int* in_sizes, int n_in,
                              void* d_out, int out_size, void* d_ws, size_t ws_size,
                              hipStream_t stream) {
    const float* x  = (const float*)d_in[0];
    const float* wq = (const float*)d_in[1];
    const float* wk = (const float*)d_in[2];
    const float* wv = (const float*)d_in[3];
    const float* Wh = (const float*)d_in[4];
    const float* bh = (const float*)d_in[5];
    const float* Wo = (const float*)d_in[6];
    const float* bo = (const float*)d_in[7];
    float* out = (float*)d_out;

    const int B = in_sizes[0] / 16;
    const int block = 256;
    const int rows_per_block = block * ROWS;
    const int grid = (B + rows_per_block - 1) / rows_per_block;
    fused_attn_mlp<<<grid, block, 0, stream>>>(x, wq, wk, wv, Wh, bh, Wo, bo, out, B);
}

// Round 5
// 133.183 us; speedup vs baseline: 1.1205x; 1.1205x over previous
//
#include <hip/hip_runtime.h>

// R3 structure (best: 55.4us) + Montgomery batch-inversion of the MLP's
// sigmoid reciprocals (64 rcp -> 16 rcp per row). R4's packed-poly exp is
// REVERTED: it scalarized the v2f dataflow and nearly doubled VALU cycles.
// Calibrated model: shared issue port; v_exp_f32/v_rcp_f32 ~16 cy per
// wave64 inst; plain/pk VALU 2 cy. Keep exps on the trans unit, minimize
// their COUNT only where exact algebra allows (rcp batching).
//
// 2 rows/thread (ILP to hide trans latency), weights in LDS (broadcast
// ds_read), packed fp32 (v_pk_fma_f32), exp2-domain softmax/sigmoid,
// per-row attained max shift (robust: no underflow/NaN mode).

typedef float v2f __attribute__((ext_vector_type(2)));

#define LOG2E 1.44269504088896340736f
#define ROWS 2

__device__ __forceinline__ float rcpf(float a) { return __builtin_amdgcn_rcpf(a); }

#if __has_builtin(__builtin_amdgcn_exp2f)
__device__ __forceinline__ float exp2_fast(float a) { return __builtin_amdgcn_exp2f(a); }
#else
__device__ __forceinline__ float exp2_fast(float a) { return __expf(0.6931471805599453f * a); }
#endif

__global__ __launch_bounds__(256, 4) void fused_attn_mlp(
    const float* __restrict__ x,
    const float* __restrict__ wq,
    const float* __restrict__ wk,
    const float* __restrict__ wv,
    const float* __restrict__ Wh,
    const float* __restrict__ bh,
    const float* __restrict__ Wo,
    const float* __restrict__ bo,
    float* __restrict__ out,
    int B)
{
    // ---- stage weights into LDS (once per block) ----
    __shared__ float sWh[64 * 16];   // row-major as given
    __shared__ float sWoT[64 * 8];   // sWoT[h*8+o] = Wo[o*64+h]
    __shared__ float sbh[64];

    const int t = threadIdx.x;
    {
        const float4* src = reinterpret_cast<const float4*>(Wh);
        float4* dst = reinterpret_cast<float4*>(sWh);
        dst[t] = src[t];
    }
    #pragma unroll
    for (int r = t; r < 512; r += 256) {
        const int h = r >> 3, o = r & 7;
        sWoT[h * 8 + o] = Wo[o * 64 + h];
    }
    if (t < 64) sbh[t] = bh[t];
    __syncthreads();

    const int b0 = blockIdx.x * (256 * ROWS) + t;
    bool valid[ROWS];
    #pragma unroll
    for (int r = 0; r < ROWS; ++r) valid[r] = (b0 + r * 256) < B;

    // ---- load x rows ----
    float xs[ROWS][16];
    v2f xv2[ROWS][8];
    #pragma unroll
    for (int r = 0; r < ROWS; ++r) {
        if (valid[r]) {
            const float4* xr = reinterpret_cast<const float4*>(x) + (size_t)(b0 + r * 256) * 4;
            float4 a0 = xr[0], a1 = xr[1], a2 = xr[2], a3 = xr[3];
            xs[r][0]=a0.x; xs[r][1]=a0.y; xs[r][2]=a0.z; xs[r][3]=a0.w;
            xs[r][4]=a1.x; xs[r][5]=a1.y; xs[r][6]=a1.z; xs[r][7]=a1.w;
            xs[r][8]=a2.x; xs[r][9]=a2.y; xs[r][10]=a2.z; xs[r][11]=a2.w;
            xs[r][12]=a3.x; xs[r][13]=a3.y; xs[r][14]=a3.z; xs[r][15]=a3.w;
        } else {
            #pragma unroll
            for (int i = 0; i < 16; ++i) xs[r][i] = 0.f;
        }
        #pragma unroll
        for (int p = 0; p < 8; ++p) { v2f v; v[0]=xs[r][2*p]; v[1]=xs[r][2*p+1]; xv2[r][p]=v; }
    }

    // ---- attention block 1 (D=16), exp2 domain ----
    const float kq1 = wk[0] * wq[0] * LOG2E;
    const float v1  = wv[0];

    float xmx[ROWS], xmn[ROWS];
    #pragma unroll
    for (int r = 0; r < ROWS; ++r) {
        float mx = xs[r][0], mn = xs[r][0];
        #pragma unroll
        for (int i = 1; i < 16; ++i) { mx = fmaxf(mx, xs[r][i]); mn = fminf(mn, xs[r][i]); }
        xmx[r] = mx; xmn[r] = mn;
    }

    v2f o1v[ROWS][8];
    #pragma unroll
    for (int r = 0; r < ROWS; ++r)
        #pragma unroll
        for (int p = 0; p < 8; ++p) o1v[r][p] = (v2f)(0.f);

    #pragma unroll
    for (int i = 0; i < 16; ++i) {
        v2f e2[ROWS][8];
        float w[ROWS];
        #pragma unroll
        for (int r = 0; r < ROWS; ++r) {
            const float c = kq1 * xs[r][i];
            const float m = fmaxf(c * xmx[r], c * xmn[r]);   // exact attained max -> args <= 0
            v2f cc; cc[0]=c; cc[1]=c;
            v2f mm; mm[0]=m; mm[1]=m;
            #pragma unroll
            for (int p = 0; p < 8; ++p) {
                v2f a = cc * xv2[r][p] - mm;                 // v_pk_fma_f32
                v2f e; e[0] = exp2_fast(a[0]); e[1] = exp2_fast(a[1]);
                e2[r][p] = e;
            }
            // tree-shaped sum (shallow dep chain)
            v2f s01 = e2[r][0] + e2[r][1];
            v2f s23 = e2[r][2] + e2[r][3];
            v2f s45 = e2[r][4] + e2[r][5];
            v2f s67 = e2[r][6] + e2[r][7];
            v2f s03 = s01 + s23;
            v2f s47 = s45 + s67;
            v2f sv  = s03 + s47;
            w[r] = v1 * xs[r][i] * rcpf(sv[0] + sv[1]);
        }
        #pragma unroll
        for (int r = 0; r < ROWS; ++r) {
            v2f ww; ww[0]=w[r]; ww[1]=w[r];
            #pragma unroll
            for (int p = 0; p < 8; ++p) o1v[r][p] += ww * e2[r][p];
        }
    }

    // ---- fused MLP: 16 -> 64 sigmoid -> 8; sigmoid rcps batch-inverted
    //      (Montgomery, groups of 4: 64 rcp -> 16 rcp per row) ----
    v2f x2v[ROWS][4];
    #pragma unroll
    for (int r = 0; r < ROWS; ++r)
        #pragma unroll
        for (int p = 0; p < 4; ++p) { v2f v; v[0]=bo[2*p]; v[1]=bo[2*p+1]; x2v[r][p]=v; }

    #pragma unroll 2
    for (int g = 0; g < 16; ++g) {
        float apre[ROWS][4];
        #pragma unroll
        for (int hh = 0; hh < 4; ++hh) {
            const int h = g * 4 + hh;
            const v2f* wh = reinterpret_cast<const v2f*>(sWh + h * 16);
            v2f whr[8];
            #pragma unroll
            for (int p = 0; p < 8; ++p) whr[p] = wh[p];      // one broadcast read, both rows
            #pragma unroll
            for (int r = 0; r < ROWS; ++r) {
                v2f acc = whr[0] * o1v[r][0];
                #pragma unroll
                for (int p = 1; p < 8; ++p) acc += whr[p] * o1v[r][p];
                apre[r][hh] = acc[0] + acc[1] + sbh[h];
            }
        }
        float sg[ROWS][4];
        #pragma unroll
        for (int r = 0; r < ROWS; ++r) {
            // la = min(-a*log2e, 30): clamp inert for a > -20.8 (sigma < 1e-9
            // there anyway); keeps d = 1+2^la <= 1+2^30 so prod4 <= 2^121.
            float d[4];
            #pragma unroll
            for (int hh = 0; hh < 4; ++hh) {
                const float la = fminf(-apre[r][hh] * LOG2E, 30.f);
                d[hh] = 1.f + exp2_fast(la);                 // trans exp kept
            }
            // Montgomery batch inversion: 1 rcp for 4 denominators
            const float p01  = d[0] * d[1];
            const float p012 = p01 * d[2];
            const float rq   = rcpf(p012 * d[3]);
            const float i3 = rq * p012;
            const float tq = rq * d[3];      // 1/(d0 d1 d2)
            const float i2 = tq * p01;
            const float t2 = tq * d[2];      // 1/(d0 d1)
            sg[r][0] = t2 * d[1];
            sg[r][1] = t2 * d[0];
            sg[r][2] = i2;
            sg[r][3] = i3;
        }
        #pragma unroll
        for (int hh = 0; hh < 4; ++hh) {
            const int h = g * 4 + hh;
            const v2f* wo = reinterpret_cast<const v2f*>(sWoT + h * 8);
            v2f wor[4];
            #pragma unroll
            for (int p = 0; p < 4; ++p) wor[p] = wo[p];
            #pragma unroll
            for (int r = 0; r < ROWS; ++r) {
                v2f sgv; sgv[0]=sg[r][hh]; sgv[1]=sg[r][hh];
                #pragma unroll
                for (int p = 0; p < 4; ++p) x2v[r][p] += wor[p] * sgv;
            }
        }
    }

    // ---- attention block 2 (D=8), exp2 domain; LOG2E folded into o2 ----
    const float kq2 = wk[1] * wq[1] * LOG2E;
    const float v2s = wv[1] * LOG2E;

    float ys[ROWS][8];
    float ymx[ROWS], ymn[ROWS];
    #pragma unroll
    for (int r = 0; r < ROWS; ++r) {
        #pragma unroll
        for (int i = 0; i < 8; ++i) ys[r][i] = x2v[r][i >> 1][i & 1];
        float mx = ys[r][0], mn = ys[r][0];
        #pragma unroll
        for (int i = 1; i < 8; ++i) { mx = fmaxf(mx, ys[r][i]); mn = fminf(mn, ys[r][i]); }
        ymx[r] = mx; ymn[r] = mn;
    }

    v2f o2v[ROWS][4];
    #pragma unroll
    for (int r = 0; r < ROWS; ++r)
        #pragma unroll
        for (int p = 0; p < 4; ++p) o2v[r][p] = (v2f)(0.f);

    #pragma unroll
    for (int i = 0; i < 8; ++i) {
        v2f e2[ROWS][4];
        float w[ROWS];
        #pragma unroll
        for (int r = 0; r < ROWS; ++r) {
            const float c = kq2 * ys[r][i];
            const float m = fmaxf(c * ymx[r], c * ymn[r]);
            v2f cc; cc[0]=c; cc[1]=c;
            v2f mm; mm[0]=m; mm[1]=m;
            #pragma unroll
            for (int p = 0; p < 4; ++p) {
                v2f a = cc * x2v[r][p] - mm;
                v2f e; e[0] = exp2_fast(a[0]); e[1] = exp2_fast(a[1]);
                e2[r][p] = e;
            }
            v2f s01 = e2[r][0] + e2[r][1];
            v2f s23 = e2[r][2] + e2[r][3];
            v2f sv  = s01 + s23;
            w[r] = v2s * ys[r][i] * rcpf(sv[0] + sv[1]);
        }
        #pragma unroll
        for (int r = 0; r < ROWS; ++r) {
            v2f ww; ww[0]=w[r]; ww[1]=w[r];
            #pragma unroll
            for (int p = 0; p < 4; ++p) o2v[r][p] += ww * e2[r][p];
        }
    }

    // ---- final softmax (log2 domain) + dot with x[8:16] ----
    #pragma unroll
    for (int r = 0; r < ROWS; ++r) {
        float o2s[8];
        #pragma unroll
        for (int i = 0; i < 8; ++i) o2s[i] = o2v[r][i >> 1][i & 1];
        float m2 = o2s[0];
        #pragma unroll
        for (int i = 1; i < 8; ++i) m2 = fmaxf(m2, o2s[i]);
        v2f mm2; mm2[0]=m2; mm2[1]=m2;
        v2f se = (v2f)(0.f), de = (v2f)(0.f);
        #pragma unroll
        for (int p = 0; p < 4; ++p) {
            v2f a = o2v[r][p] - mm2;
            v2f e; e[0] = exp2_fast(a[0]); e[1] = exp2_fast(a[1]);
            se += e;
            v2f xp; xp[0]=xs[r][8+2*p]; xp[1]=xs[r][9+2*p];
            de += xp * e;
        }
        if (valid[r]) out[b0 + r * 256] = (de[0] + de[1]) * rcpf(se[0] + se[1]);
    }
}

extern "C" void kernel_launch(void* const* d_in, const int* in_sizes, int n_in,
                              void* d_out, int out_size, void* d_ws, size_t ws_size,
                              hipStream_t stream) {
    const float* x  = (const float*)d_in[0];
    const float* wq = (const float*)d_in[1];
    const float* wk = (const float*)d_in[2];
    const float* wv = (const float*)d_in[3];
    const float* Wh = (const float*)d_in[4];
    const float* bh = (const float*)d_in[5];
    const float* Wo = (const float*)d_in[6];
    const float* bo = (const float*)d_in[7];
    float* out = (float*)d_out;

    const int B = in_sizes[0] / 16;
    const int block = 256;
    const int rows_per_block = block * ROWS;
    const int grid = (B + rows_per_block - 1) / rows_per_block;
    fused_attn_mlp<<<grid, block, 0, stream>>>(x, wq, wk, wv, Wh, bh, Wo, bo, out, B);
}

// Round 6
// 129.442 us; speedup vs baseline: 1.1529x; 1.0289x over previous
//
#include <hip/hip_runtime.h>

// R6: ROWS=4 — four independent per-row dependency chains per thread.
// Rationale (calibrated R2-R5): elapsed ~= issue_demand / busy_eff with
// busy_eff stuck at 0.60-0.64 across occupancy configs; demand is fixed
// (trans-dominated: v_exp/v_rcp ~16cy per wave64 inst, no safe algebraic
// reduction left); 1-row->2-row ILP moved busy 60->64%, so push ILP to 4
// chains to fill the exp->sum->rcp dependency-stall windows. Grid 512,
// 2 waves/SIMD, single generation, all waves resident.
// Also: x global loads issued BEFORE LDS weight staging (HBM latency hides
// under staging + barrier).
// Kept from R5: LDS-staged weights (broadcast ds_read, now amortized over
// 4 rows), packed fp32 (v_pk_fma_f32), exp2-domain softmax/sigmoid with
// per-row attained-max shift (robust), Montgomery-batched sigmoid rcps.

typedef float v2f __attribute__((ext_vector_type(2)));

#define LOG2E 1.44269504088896340736f
#define ROWS 4

__device__ __forceinline__ float rcpf(float a) { return __builtin_amdgcn_rcpf(a); }

#if __has_builtin(__builtin_amdgcn_exp2f)
__device__ __forceinline__ float exp2_fast(float a) { return __builtin_amdgcn_exp2f(a); }
#else
__device__ __forceinline__ float exp2_fast(float a) { return __expf(0.6931471805599453f * a); }
#endif

__global__ __launch_bounds__(256, 2) void fused_attn_mlp(
    const float* __restrict__ x,
    const float* __restrict__ wq,
    const float* __restrict__ wk,
    const float* __restrict__ wv,
    const float* __restrict__ Wh,
    const float* __restrict__ bh,
    const float* __restrict__ Wo,
    const float* __restrict__ bo,
    float* __restrict__ out,
    int B)
{
    const int t = threadIdx.x;
    const int b0 = blockIdx.x * (256 * ROWS) + t;

    bool valid[ROWS];
    #pragma unroll
    for (int r = 0; r < ROWS; ++r) valid[r] = (b0 + r * 256) < B;

    // ---- issue x loads FIRST (latency hides under weight staging+barrier) ----
    float4 xraw[ROWS][4];
    #pragma unroll
    for (int r = 0; r < ROWS; ++r) {
        if (valid[r]) {
            const float4* xr = reinterpret_cast<const float4*>(x) + (size_t)(b0 + r * 256) * 4;
            xraw[r][0] = xr[0]; xraw[r][1] = xr[1]; xraw[r][2] = xr[2]; xraw[r][3] = xr[3];
        } else {
            xraw[r][0] = xraw[r][1] = xraw[r][2] = xraw[r][3] = float4{0.f,0.f,0.f,0.f};
        }
    }

    // ---- stage weights into LDS (once per block) ----
    __shared__ float sWh[64 * 16];   // row-major as given
    __shared__ float sWoT[64 * 8];   // sWoT[h*8+o] = Wo[o*64+h]
    __shared__ float sbh[64];
    {
        const float4* src = reinterpret_cast<const float4*>(Wh);
        float4* dst = reinterpret_cast<float4*>(sWh);
        dst[t] = src[t];
    }
    #pragma unroll
    for (int r = t; r < 512; r += 256) {
        const int h = r >> 3, o = r & 7;
        sWoT[h * 8 + o] = Wo[o * 64 + h];
    }
    if (t < 64) sbh[t] = bh[t];
    __syncthreads();

    // ---- unpack x rows ----
    float xs[ROWS][16];
    v2f xv2[ROWS][8];
    #pragma unroll
    for (int r = 0; r < ROWS; ++r) {
        xs[r][0]=xraw[r][0].x; xs[r][1]=xraw[r][0].y; xs[r][2]=xraw[r][0].z; xs[r][3]=xraw[r][0].w;
        xs[r][4]=xraw[r][1].x; xs[r][5]=xraw[r][1].y; xs[r][6]=xraw[r][1].z; xs[r][7]=xraw[r][1].w;
        xs[r][8]=xraw[r][2].x; xs[r][9]=xraw[r][2].y; xs[r][10]=xraw[r][2].z; xs[r][11]=xraw[r][2].w;
        xs[r][12]=xraw[r][3].x; xs[r][13]=xraw[r][3].y; xs[r][14]=xraw[r][3].z; xs[r][15]=xraw[r][3].w;
        #pragma unroll
        for (int p = 0; p < 8; ++p) { v2f v; v[0]=xs[r][2*p]; v[1]=xs[r][2*p+1]; xv2[r][p]=v; }
    }

    // ---- attention block 1 (D=16), exp2 domain ----
    const float kq1 = wk[0] * wq[0] * LOG2E;
    const float v1  = wv[0];

    float xmx[ROWS], xmn[ROWS];
    #pragma unroll
    for (int r = 0; r < ROWS; ++r) {
        float mx = xs[r][0], mn = xs[r][0];
        #pragma unroll
        for (int i = 1; i < 16; ++i) { mx = fmaxf(mx, xs[r][i]); mn = fminf(mn, xs[r][i]); }
        xmx[r] = mx; xmn[r] = mn;
    }

    v2f o1v[ROWS][8];
    #pragma unroll
    for (int r = 0; r < ROWS; ++r)
        #pragma unroll
        for (int p = 0; p < 8; ++p) o1v[r][p] = (v2f)(0.f);

    #pragma unroll
    for (int i = 0; i < 16; ++i) {
        v2f e2[ROWS][8];
        float w[ROWS];
        #pragma unroll
        for (int r = 0; r < ROWS; ++r) {
            const float c = kq1 * xs[r][i];
            const float m = fmaxf(c * xmx[r], c * xmn[r]);   // exact attained max -> args <= 0
            v2f cc; cc[0]=c; cc[1]=c;
            v2f mm; mm[0]=m; mm[1]=m;
            #pragma unroll
            for (int p = 0; p < 8; ++p) {
                v2f a = cc * xv2[r][p] - mm;                 // v_pk_fma_f32
                v2f e; e[0] = exp2_fast(a[0]); e[1] = exp2_fast(a[1]);
                e2[r][p] = e;
            }
            v2f s01 = e2[r][0] + e2[r][1];
            v2f s23 = e2[r][2] + e2[r][3];
            v2f s45 = e2[r][4] + e2[r][5];
            v2f s67 = e2[r][6] + e2[r][7];
            v2f sv  = (s01 + s23) + (s45 + s67);
            w[r] = v1 * xs[r][i] * rcpf(sv[0] + sv[1]);
        }
        #pragma unroll
        for (int r = 0; r < ROWS; ++r) {
            v2f ww; ww[0]=w[r]; ww[1]=w[r];
            #pragma unroll
            for (int p = 0; p < 8; ++p) o1v[r][p] += ww * e2[r][p];
        }
    }

    // ---- fused MLP: 16 -> 64 sigmoid -> 8; sigmoid rcps batch-inverted
    //      (Montgomery, groups of 4). One LDS broadcast serves 4 rows. ----
    v2f x2v[ROWS][4];
    #pragma unroll
    for (int r = 0; r < ROWS; ++r)
        #pragma unroll
        for (int p = 0; p < 4; ++p) { v2f v; v[0]=bo[2*p]; v[1]=bo[2*p+1]; x2v[r][p]=v; }

    #pragma unroll 2
    for (int g = 0; g < 16; ++g) {
        float apre[ROWS][4];
        #pragma unroll
        for (int hh = 0; hh < 4; ++hh) {
            const int h = g * 4 + hh;
            const v2f* wh = reinterpret_cast<const v2f*>(sWh + h * 16);
            v2f whr[8];
            #pragma unroll
            for (int p = 0; p < 8; ++p) whr[p] = wh[p];
            #pragma unroll
            for (int r = 0; r < ROWS; ++r) {
                v2f acc = whr[0] * o1v[r][0];
                #pragma unroll
                for (int p = 1; p < 8; ++p) acc += whr[p] * o1v[r][p];
                apre[r][hh] = acc[0] + acc[1] + sbh[h];
            }
        }
        float sg[ROWS][4];
        #pragma unroll
        for (int r = 0; r < ROWS; ++r) {
            // clamp inert for a > -20.8 (sigma < 1e-9 there); keeps
            // d = 1+2^la <= 1+2^30, so prod4 <= 2^121 (no overflow).
            float d[4];
            #pragma unroll
            for (int hh = 0; hh < 4; ++hh) {
                const float la = fminf(-apre[r][hh] * LOG2E, 30.f);
                d[hh] = 1.f + exp2_fast(la);
            }
            const float p01  = d[0] * d[1];
            const float p012 = p01 * d[2];
            const float rq   = rcpf(p012 * d[3]);
            const float i3 = rq * p012;
            const float tq = rq * d[3];      // 1/(d0 d1 d2)
            const float i2 = tq * p01;
            const float t2 = tq * d[2];      // 1/(d0 d1)
            sg[r][0] = t2 * d[1];
            sg[r][1] = t2 * d[0];
            sg[r][2] = i2;
            sg[r][3] = i3;
        }
        #pragma unroll
        for (int hh = 0; hh < 4; ++hh) {
            const int h = g * 4 + hh;
            const v2f* wo = reinterpret_cast<const v2f*>(sWoT + h * 8);
            v2f wor[4];
            #pragma unroll
            for (int p = 0; p < 4; ++p) wor[p] = wo[p];
            #pragma unroll
            for (int r = 0; r < ROWS; ++r) {
                v2f sgv; sgv[0]=sg[r][hh]; sgv[1]=sg[r][hh];
                #pragma unroll
                for (int p = 0; p < 4; ++p) x2v[r][p] += wor[p] * sgv;
            }
        }
    }

    // ---- attention block 2 (D=8), exp2 domain; LOG2E folded into o2 ----
    const float kq2 = wk[1] * wq[1] * LOG2E;
    const float v2s = wv[1] * LOG2E;

    float ys[ROWS][8];
    float ymx[ROWS], ymn[ROWS];
    #pragma unroll
    for (int r = 0; r < ROWS; ++r) {
        #pragma unroll
        for (int i = 0; i < 8; ++i) ys[r][i] = x2v[r][i >> 1][i & 1];
        float mx = ys[r][0], mn = ys[r][0];
        #pragma unroll
        for (int i = 1; i < 8; ++i) { mx = fmaxf(mx, ys[r][i]); mn = fminf(mn, ys[r][i]); }
        ymx[r] = mx; ymn[r] = mn;
    }

    v2f o2v[ROWS][4];
    #pragma unroll
    for (int r = 0; r < ROWS; ++r)
        #pragma unroll
        for (int p = 0; p < 4; ++p) o2v[r][p] = (v2f)(0.f);

    #pragma unroll
    for (int i = 0; i < 8; ++i) {
        v2f e2[ROWS][4];
        float w[ROWS];
        #pragma unroll
        for (int r = 0; r < ROWS; ++r) {
            const float c = kq2 * ys[r][i];
            const float m = fmaxf(c * ymx[r], c * ymn[r]);
            v2f cc; cc[0]=c; cc[1]=c;
            v2f mm; mm[0]=m; mm[1]=m;
            #pragma unroll
            for (int p = 0; p < 4; ++p) {
                v2f a = cc * x2v[r][p] - mm;
                v2f e; e[0] = exp2_fast(a[0]); e[1] = exp2_fast(a[1]);
                e2[r][p] = e;
            }
            v2f sv = (e2[r][0] + e2[r][1]) + (e2[r][2] + e2[r][3]);
            w[r] = v2s * ys[r][i] * rcpf(sv[0] + sv[1]);
        }
        #pragma unroll
        for (int r = 0; r < ROWS; ++r) {
            v2f ww; ww[0]=w[r]; ww[1]=w[r];
            #pragma unroll
            for (int p = 0; p < 4; ++p) o2v[r][p] += ww * e2[r][p];
        }
    }

    // ---- final softmax (log2 domain) + dot with x[8:16] ----
    #pragma unroll
    for (int r = 0; r < ROWS; ++r) {
        float o2s[8];
        #pragma unroll
        for (int i = 0; i < 8; ++i) o2s[i] = o2v[r][i >> 1][i & 1];
        float m2 = o2s[0];
        #pragma unroll
        for (int i = 1; i < 8; ++i) m2 = fmaxf(m2, o2s[i]);
        v2f mm2; mm2[0]=m2; mm2[1]=m2;
        v2f se = (v2f)(0.f), de = (v2f)(0.f);
        #pragma unroll
        for (int p = 0; p < 4; ++p) {
            v2f a = o2v[r][p] - mm2;
            v2f e; e[0] = exp2_fast(a[0]); e[1] = exp2_fast(a[1]);
            se += e;
            v2f xp; xp[0]=xs[r][8+2*p]; xp[1]=xs[r][9+2*p];
            de += xp * e;
        }
        if (valid[r]) out[b0 + r * 256] = (de[0] + de[1]) * rcpf(se[0] + se[1]);
    }
}

extern "C" void kernel_launch(void* const* d_in, const int* in_sizes, int n_in,
                              void* d_out, int out_size, void* d_ws, size_t ws_size,
                              hipStream_t stream) {
    const float* x  = (const float*)d_in[0];
    const float* wq = (const float*)d_in[1];
    const float* wk = (const float*)d_in[2];
    const float* wv = (const float*)d_in[3];
    const float* Wh = (const float*)d_in[4];
    const float* bh = (const float*)d_in[5];
    const float* Wo = (const float*)d_in[6];
    const float* bo = (const float*)d_in[7];
    float* out = (float*)d_out;

    const int B = in_sizes[0] / 16;
    const int block = 256;
    const int rows_per_block = block * ROWS;
    const int grid = (B + rows_per_block - 1) / rows_per_block;
    fused_attn_mlp<<<grid, block, 0, stream>>>(x, wq, wk, wv, Wh, bh, Wo, bo, out, B);
}

// Round 7
// 126.978 us; speedup vs baseline: 1.1753x; 1.0194x over previous
//
#include <hip/hip_runtime.h>

// R7: R5 structure (best: 55.4us) with ALL LDS removed. Weights are read at
// wave-uniform indices straight from global __restrict__ pointers -> compiler
// emits batched s_load (scalar pipe, zero VALU issue slots, deep lookahead).
// Evidence: R1 (s_load weights) ran at 0.71 issue-efficiency vs 0.60-0.64 for
// every LDS-based variant (R2-R6) — the MLP's just-in-time ds_reads were a
// chunk of the ~36% idle. Also removes LDS staging + the only barrier.
// ROWS=4 (R6) regressed -> back to ROWS=2.
// Kept: packed fp32 (v_pk_fma_f32), exp2-domain softmax/sigmoid with per-row
// attained-max shift (robust, no underflow), Montgomery-batched sigmoid rcps,
// tree sums, x loads issued first.

typedef float v2f __attribute__((ext_vector_type(2)));

#define LOG2E 1.44269504088896340736f
#define ROWS 2

__device__ __forceinline__ float rcpf(float a) { return __builtin_amdgcn_rcpf(a); }

#if __has_builtin(__builtin_amdgcn_exp2f)
__device__ __forceinline__ float exp2_fast(float a) { return __builtin_amdgcn_exp2f(a); }
#else
__device__ __forceinline__ float exp2_fast(float a) { return __expf(0.6931471805599453f * a); }
#endif

__global__ __launch_bounds__(256, 4) void fused_attn_mlp(
    const float* __restrict__ x,
    const float* __restrict__ wq,
    const float* __restrict__ wk,
    const float* __restrict__ wv,
    const float* __restrict__ Wh,
    const float* __restrict__ bh,
    const float* __restrict__ Wo,
    const float* __restrict__ bo,
    float* __restrict__ out,
    int B)
{
    const int t = threadIdx.x;
    const int b0 = blockIdx.x * (256 * ROWS) + t;

    bool valid[ROWS];
    #pragma unroll
    for (int r = 0; r < ROWS; ++r) valid[r] = (b0 + r * 256) < B;

    // ---- issue x loads first (VMEM latency hides under s_load setup) ----
    float4 xraw[ROWS][4];
    #pragma unroll
    for (int r = 0; r < ROWS; ++r) {
        if (valid[r]) {
            const float4* xr = reinterpret_cast<const float4*>(x) + (size_t)(b0 + r * 256) * 4;
            xraw[r][0] = xr[0]; xraw[r][1] = xr[1]; xraw[r][2] = xr[2]; xraw[r][3] = xr[3];
        } else {
            xraw[r][0] = xraw[r][1] = xraw[r][2] = xraw[r][3] = float4{0.f,0.f,0.f,0.f};
        }
    }

    // ---- unpack x rows ----
    float xs[ROWS][16];
    v2f xv2[ROWS][8];
    #pragma unroll
    for (int r = 0; r < ROWS; ++r) {
        xs[r][0]=xraw[r][0].x; xs[r][1]=xraw[r][0].y; xs[r][2]=xraw[r][0].z; xs[r][3]=xraw[r][0].w;
        xs[r][4]=xraw[r][1].x; xs[r][5]=xraw[r][1].y; xs[r][6]=xraw[r][1].z; xs[r][7]=xraw[r][1].w;
        xs[r][8]=xraw[r][2].x; xs[r][9]=xraw[r][2].y; xs[r][10]=xraw[r][2].z; xs[r][11]=xraw[r][2].w;
        xs[r][12]=xraw[r][3].x; xs[r][13]=xraw[r][3].y; xs[r][14]=xraw[r][3].z; xs[r][15]=xraw[r][3].w;
        #pragma unroll
        for (int p = 0; p < 8; ++p) { v2f v; v[0]=xs[r][2*p]; v[1]=xs[r][2*p+1]; xv2[r][p]=v; }
    }

    // ---- attention block 1 (D=16), exp2 domain ----
    const float kq1 = wk[0] * wq[0] * LOG2E;
    const float v1  = wv[0];

    float xmx[ROWS], xmn[ROWS];
    #pragma unroll
    for (int r = 0; r < ROWS; ++r) {
        float mx = xs[r][0], mn = xs[r][0];
        #pragma unroll
        for (int i = 1; i < 16; ++i) { mx = fmaxf(mx, xs[r][i]); mn = fminf(mn, xs[r][i]); }
        xmx[r] = mx; xmn[r] = mn;
    }

    v2f o1v[ROWS][8];
    #pragma unroll
    for (int r = 0; r < ROWS; ++r)
        #pragma unroll
        for (int p = 0; p < 8; ++p) o1v[r][p] = (v2f)(0.f);

    #pragma unroll
    for (int i = 0; i < 16; ++i) {
        v2f e2[ROWS][8];
        float w[ROWS];
        #pragma unroll
        for (int r = 0; r < ROWS; ++r) {
            const float c = kq1 * xs[r][i];
            const float m = fmaxf(c * xmx[r], c * xmn[r]);   // exact attained max -> args <= 0
            v2f cc; cc[0]=c; cc[1]=c;
            v2f mm; mm[0]=m; mm[1]=m;
            #pragma unroll
            for (int p = 0; p < 8; ++p) {
                v2f a = cc * xv2[r][p] - mm;                 // v_pk_fma_f32
                v2f e; e[0] = exp2_fast(a[0]); e[1] = exp2_fast(a[1]);
                e2[r][p] = e;
            }
            v2f s01 = e2[r][0] + e2[r][1];
            v2f s23 = e2[r][2] + e2[r][3];
            v2f s45 = e2[r][4] + e2[r][5];
            v2f s67 = e2[r][6] + e2[r][7];
            v2f sv  = (s01 + s23) + (s45 + s67);
            w[r] = v1 * xs[r][i] * rcpf(sv[0] + sv[1]);
        }
        #pragma unroll
        for (int r = 0; r < ROWS; ++r) {
            v2f ww; ww[0]=w[r]; ww[1]=w[r];
            #pragma unroll
            for (int p = 0; p < 8; ++p) o1v[r][p] += ww * e2[r][p];
        }
    }

    // ---- fused MLP: 16 -> 64 sigmoid -> 8. Weights read at UNIFORM global
    //      indices -> s_load (scalar pipe). Sigmoid rcps Montgomery-batched. ----
    v2f x2v[ROWS][4];
    #pragma unroll
    for (int r = 0; r < ROWS; ++r)
        #pragma unroll
        for (int p = 0; p < 4; ++p) { v2f v; v[0]=bo[2*p]; v[1]=bo[2*p+1]; x2v[r][p]=v; }

    const v2f* Wh2 = reinterpret_cast<const v2f*>(Wh);   // [64][8] pairs
    const v2f* Wo2 = reinterpret_cast<const v2f*>(Wo);   // [8][32] pairs

    #pragma unroll 2
    for (int g = 0; g < 16; ++g) {
        float apre[ROWS][4];
        #pragma unroll
        for (int hh = 0; hh < 4; ++hh) {
            const int h = g * 4 + hh;
            v2f whr[8];
            #pragma unroll
            for (int p = 0; p < 8; ++p) whr[p] = Wh2[h * 8 + p];   // uniform -> s_load
            const float bhh = bh[h];
            #pragma unroll
            for (int r = 0; r < ROWS; ++r) {
                v2f acc = whr[0] * o1v[r][0];
                #pragma unroll
                for (int p = 1; p < 8; ++p) acc += whr[p] * o1v[r][p];
                apre[r][hh] = acc[0] + acc[1] + bhh;
            }
        }
        float sg[ROWS][4];
        #pragma unroll
        for (int r = 0; r < ROWS; ++r) {
            // clamp inert for a > -20.8 (sigma < 1e-9 there); keeps
            // d = 1+2^la <= 1+2^30, so prod4 <= 2^121 (no overflow).
            float d[4];
            #pragma unroll
            for (int hh = 0; hh < 4; ++hh) {
                const float la = fminf(-apre[r][hh] * LOG2E, 30.f);
                d[hh] = 1.f + exp2_fast(la);
            }
            const float p01  = d[0] * d[1];
            const float p012 = p01 * d[2];
            const float rq   = rcpf(p012 * d[3]);
            const float i3 = rq * p012;
            const float tq = rq * d[3];      // 1/(d0 d1 d2)
            const float i2 = tq * p01;
            const float t2 = tq * d[2];      // 1/(d0 d1)
            sg[r][0] = t2 * d[1];
            sg[r][1] = t2 * d[0];
            sg[r][2] = i2;
            sg[r][3] = i3;
        }
        // x2[o] += Wo[o][h] * sg[h] for the 4 h's of this group; Wo accessed
        // at uniform indices (o compile-time, h unrolled) -> s_load.
        #pragma unroll
        for (int hh = 0; hh < 4; ++hh) {
            const int h = g * 4 + hh;
            #pragma unroll
            for (int p = 0; p < 4; ++p) {      // p = output pair (o = 2p, 2p+1)
                v2f wo2;
                wo2[0] = Wo[(2 * p) * 64 + h];       // uniform scalar loads
                wo2[1] = Wo[(2 * p + 1) * 64 + h];
                #pragma unroll
                for (int r = 0; r < ROWS; ++r) {
                    v2f sgv; sgv[0] = sg[r][hh]; sgv[1] = sg[r][hh];
                    x2v[r][p] += wo2 * sgv;
                }
            }
        }
    }

    // ---- attention block 2 (D=8), exp2 domain; LOG2E folded into o2 ----
    const float kq2 = wk[1] * wq[1] * LOG2E;
    const float v2s = wv[1] * LOG2E;

    float ys[ROWS][8];
    float ymx[ROWS], ymn[ROWS];
    #pragma unroll
    for (int r = 0; r < ROWS; ++r) {
        #pragma unroll
        for (int i = 0; i < 8; ++i) ys[r][i] = x2v[r][i >> 1][i & 1];
        float mx = ys[r][0], mn = ys[r][0];
        #pragma unroll
        for (int i = 1; i < 8; ++i) { mx = fmaxf(mx, ys[r][i]); mn = fminf(mn, ys[r][i]); }
        ymx[r] = mx; ymn[r] = mn;
    }

    v2f o2v[ROWS][4];
    #pragma unroll
    for (int r = 0; r < ROWS; ++r)
        #pragma unroll
        for (int p = 0; p < 4; ++p) o2v[r][p] = (v2f)(0.f);

    #pragma unroll
    for (int i = 0; i < 8; ++i) {
        v2f e2[ROWS][4];
        float w[ROWS];
        #pragma unroll
        for (int r = 0; r < ROWS; ++r) {
            const float c = kq2 * ys[r][i];
            const float m = fmaxf(c * ymx[r], c * ymn[r]);
            v2f cc; cc[0]=c; cc[1]=c;
            v2f mm; mm[0]=m; mm[1]=m;
            #pragma unroll
            for (int p = 0; p < 4; ++p) {
                v2f a = cc * x2v[r][p] - mm;
                v2f e; e[0] = exp2_fast(a[0]); e[1] = exp2_fast(a[1]);
                e2[r][p] = e;
            }
            v2f sv = (e2[r][0] + e2[r][1]) + (e2[r][2] + e2[r][3]);
            w[r] = v2s * ys[r][i] * rcpf(sv[0] + sv[1]);
        }
        #pragma unroll
        for (int r = 0; r < ROWS; ++r) {
            v2f ww; ww[0]=w[r]; ww[1]=w[r];
            #pragma unroll
            for (int p = 0; p < 4; ++p) o2v[r][p] += ww * e2[r][p];
        }
    }

    // ---- final softmax (log2 domain) + dot with x[8:16] ----
    #pragma unroll
    for (int r = 0; r < ROWS; ++r) {
        float o2s[8];
        #pragma unroll
        for (int i = 0; i < 8; ++i) o2s[i] = o2v[r][i >> 1][i & 1];
        float m2 = o2s[0];
        #pragma unroll
        for (int i = 1; i < 8; ++i) m2 = fmaxf(m2, o2s[i]);
        v2f mm2; mm2[0]=m2; mm2[1]=m2;
        v2f se = (v2f)(0.f), de = (v2f)(0.f);
        #pragma unroll
        for (int p = 0; p < 4; ++p) {
            v2f a = o2v[r][p] - mm2;
            v2f e; e[0] = exp2_fast(a[0]); e[1] = exp2_fast(a[1]);
            se += e;
            v2f xp; xp[0]=xs[r][8+2*p]; xp[1]=xs[r][9+2*p];
            de += xp * e;
        }
        if (valid[r]) out[b0 + r * 256] = (de[0] + de[1]) * rcpf(se[0] + se[1]);
    }
}

extern "C" void kernel_launch(void* const* d_in, const int* in_sizes, int n_in,
                              void* d_out, int out_size, void* d_ws, size_t ws_size,
                              hipStream_t stream) {
    const float* x  = (const float*)d_in[0];
    const float* wq = (const float*)d_in[1];
    const float* wk = (const float*)d_in[2];
    const float* wv = (const float*)d_in[3];
    const float* Wh = (const float*)d_in[4];
    const float* bh = (const float*)d_in[5];
    const float* Wo = (const float*)d_in[6];
    const float* bo = (const float*)d_in[7];
    float* out = (float*)d_out;

    const int B = in_sizes[0] / 16;
    const int block = 256;
    const int rows_per_block = block * ROWS;
    const int grid = (B + rows_per_block - 1) / rows_per_block;
    fused_attn_mlp<<<grid, block, 0, stream>>>(x, wq, wk, wv, Wh, bh, Wo, bo, out, B);
}